// Round 1
// baseline (483.550 us; speedup 1.0000x reference)
//
#include <hip/hip_runtime.h>
#include <hip/hip_bf16.h>

typedef __bf16 bf16x8 __attribute__((ext_vector_type(8)));
typedef float  f32x4  __attribute__((ext_vector_type(4)));
typedef unsigned int uint4v __attribute__((ext_vector_type(4)));

#define LOG2E 1.4426950408889634f

__device__ __forceinline__ unsigned int pk2(float a, float b) {
  unsigned short lo = __builtin_bit_cast(unsigned short, (__bf16)a);
  unsigned short hi = __builtin_bit_cast(unsigned short, (__bf16)b);
  return (unsigned int)lo | ((unsigned int)hi << 16);
}

// ---------------- pred1 = (f_t @ W1^T + b1) * log2e  -> bf16 [512][128] ----
__global__ __launch_bounds__(256) void pred1_kernel(
    const float* __restrict__ f_t, const float* __restrict__ W1,
    const float* __restrict__ b1, unsigned short* __restrict__ pred1) {
  int t = blockIdx.x * 256 + threadIdx.x;   // 65536 threads
  int n = t >> 7, d = t & 127;
  const float4* fr = (const float4*)(f_t + n * 256);
  const float4* wr = (const float4*)(W1 + d * 256);
  float acc = 0.f;
#pragma unroll 16
  for (int e = 0; e < 64; ++e) {
    float4 a = fr[e], b = wr[e];
    acc += a.x * b.x; acc += a.y * b.y; acc += a.z * b.z; acc += a.w * b.w;
  }
  float v = (acc + b1[d]) * LOG2E;
  pred1[t] = __builtin_bit_cast(unsigned short, (__bf16)v);
}

// -------- pred2[yx] = (fmap_t[:,y,x,:] @ W2^T + b2) * log2e -> bf16 --------
__global__ __launch_bounds__(512, 2) void pred2_kernel(
    const float* __restrict__ fmap_t, const float* __restrict__ W2,
    const float* __restrict__ b2, unsigned short* __restrict__ pred2) {
  __shared__ unsigned short w2s[16384];   // swizzled bf16 W2 [d][e], 32KB
  const int yx = blockIdx.x;
  const int tid = threadIdx.x;
  {
    const int r = tid >> 2, q = tid & 3;
    const float4* src = (const float4*)(W2 + r * 128 + q * 32);
    char* buf = (char*)w2s;
#pragma unroll
    for (int j = 0; j < 4; ++j) {
      float4 f0 = src[2 * j], f1 = src[2 * j + 1];
      uint4v pk = { pk2(f0.x, f0.y), pk2(f0.z, f0.w),
                    pk2(f1.x, f1.y), pk2(f1.z, f1.w) };
      int byte = r * 256 + ((q * 64 + j * 16) ^ ((r & 7) << 4));
      *(uint4v*)(buf + byte) = pk;
    }
  }
  const int w = tid >> 6, lane = tid & 63;
  const int lo16 = lane & 15, hi4 = lane >> 4;

  // A fragments: fmap_t slice rows (64 per wave), bf16
  bf16x8 a[4][4];
#pragma unroll
  for (int mt = 0; mt < 4; ++mt)
#pragma unroll
    for (int ks = 0; ks < 4; ++ks) {
      int row = w * 64 + 16 * mt + lo16;
      int k = 32 * ks + 8 * hi4;
      const float* p = fmap_t + (size_t)row * 32768 + yx * 128 + k;
      float4 f0 = ((const float4*)p)[0], f1 = ((const float4*)p)[1];
      bf16x8 av;
      av[0] = (__bf16)f0.x; av[1] = (__bf16)f0.y; av[2] = (__bf16)f0.z; av[3] = (__bf16)f0.w;
      av[4] = (__bf16)f1.x; av[5] = (__bf16)f1.y; av[6] = (__bf16)f1.z; av[7] = (__bf16)f1.w;
      a[mt][ks] = av;
    }
  __syncthreads();

  unsigned short* outb = pred2 + (size_t)yx * 65536;
#pragma unroll
  for (int nt = 0; nt < 8; ++nt) {
    bf16x8 bw[4];
#pragma unroll
    for (int ks = 0; ks < 4; ++ks) {
      int m = nt * 16 + lo16;
      int kb = (32 * ks + 8 * hi4) * 2;
      bw[ks] = *(const bf16x8*)((const char*)w2s + m * 256 + (kb ^ ((m & 7) << 4)));
    }
    float b2v = b2[nt * 16 + lo16];
#pragma unroll
    for (int mt = 0; mt < 4; ++mt) {
      f32x4 acc = {0.f, 0.f, 0.f, 0.f};
#pragma unroll
      for (int ks = 0; ks < 4; ++ks)
        acc = __builtin_amdgcn_mfma_f32_16x16x32_bf16(a[mt][ks], bw[ks], acc, 0, 0, 0);
      int row = w * 64 + 16 * mt + hi4 * 4;
      int dcol = nt * 16 + lo16;
#pragma unroll
      for (int r = 0; r < 4; ++r) {
        float v = (acc[r] + b2v) * LOG2E;
        outb[(size_t)(row + r) * 128 + dcol] = __builtin_bit_cast(unsigned short, (__bf16)v);
      }
    }
  }
}

// ------------- main: per (y,x): lse rows of A{1,2} @ B^T, minus diag -------
__global__ __launch_bounds__(512, 2) void loss_kernel(
    const float* __restrict__ fmap_tp1,
    const unsigned short* __restrict__ pred1,
    const unsigned short* __restrict__ pred2,
    float* __restrict__ out) {
  __shared__ unsigned short Bs[2][16384];   // 2 x 32KB swizzled bf16 B-chunks
  const int yx = blockIdx.x;
  const int tid = threadIdx.x;
  const int w = tid >> 6, lane = tid & 63;
  const int lo16 = lane & 15, hi4 = lane >> 4;
  const int sr = tid >> 2, sq = tid & 3;    // staging row / quarter

  // A fragments for both branches (held in registers the whole kernel)
  bf16x8 a1[4][4], a2[4][4];
  const unsigned short* p2s = pred2 + (size_t)yx * 65536;
#pragma unroll
  for (int mt = 0; mt < 4; ++mt)
#pragma unroll
    for (int ks = 0; ks < 4; ++ks) {
      int row = w * 64 + 16 * mt + lo16;
      int k = 32 * ks + 8 * hi4;
      a1[mt][ks] = *(const bf16x8*)(pred1 + row * 128 + k);
      a2[mt][ks] = *(const bf16x8*)(p2s + row * 128 + k);
    }

  float s1[4][4], s2[4][4];
#pragma unroll
  for (int mt = 0; mt < 4; ++mt)
#pragma unroll
    for (int r = 0; r < 4; ++r) { s1[mt][r] = 0.f; s2[mt][r] = 0.f; }
  float diag = 0.f;

  const float* srcbase = fmap_tp1 + (size_t)sr * 32768 + yx * 128 + sq * 32;
  float4 tmp[8];
  // stage chunk 0 (load + convert + swizzled LDS write)
#pragma unroll
  for (int j = 0; j < 8; ++j) tmp[j] = ((const float4*)srcbase)[j];
  {
    char* buf = (char*)Bs[0];
#pragma unroll
    for (int j = 0; j < 4; ++j) {
      float4 f0 = tmp[2 * j], f1 = tmp[2 * j + 1];
      uint4v pk = { pk2(f0.x, f0.y), pk2(f0.z, f0.w),
                    pk2(f1.x, f1.y), pk2(f1.z, f1.w) };
      int byte = sr * 256 + ((sq * 64 + j * 16) ^ ((sr & 7) << 4));
      *(uint4v*)(buf + byte) = pk;
    }
  }
  __syncthreads();

  for (int c = 0; c < 4; ++c) {
    if (c < 3) {   // T14: issue next chunk's global loads early
      const float4* src = (const float4*)(srcbase + (size_t)(c + 1) * 128 * 32768);
#pragma unroll
      for (int j = 0; j < 8; ++j) tmp[j] = src[j];
    }
    const char* buf = (const char*)Bs[c & 1];
#pragma unroll
    for (int nt = 0; nt < 8; ++nt) {
      bf16x8 bw[4];
#pragma unroll
      for (int ks = 0; ks < 4; ++ks) {
        int m = nt * 16 + lo16;
        int kb = (32 * ks + 8 * hi4) * 2;
        bw[ks] = *(const bf16x8*)(buf + m * 256 + (kb ^ ((m & 7) << 4)));
      }
      const int coltile = c * 128 + nt * 16;
#pragma unroll
      for (int mt = 0; mt < 4; ++mt) {
        f32x4 acc = {0.f, 0.f, 0.f, 0.f};
#pragma unroll
        for (int ks = 0; ks < 4; ++ks)
          acc = __builtin_amdgcn_mfma_f32_16x16x32_bf16(a1[mt][ks], bw[ks], acc, 0, 0, 0);
        f32x4 acc2 = {0.f, 0.f, 0.f, 0.f};
#pragma unroll
        for (int ks = 0; ks < 4; ++ks)
          acc2 = __builtin_amdgcn_mfma_f32_16x16x32_bf16(a2[mt][ks], bw[ks], acc2, 0, 0, 0);
#pragma unroll
        for (int r = 0; r < 4; ++r) {
          s1[mt][r] += __builtin_amdgcn_exp2f(acc[r]);
          s2[mt][r] += __builtin_amdgcn_exp2f(acc2[r]);
        }
        if (coltile == w * 64 + mt * 16) {   // diagonal tile (wave-uniform)
#pragma unroll
          for (int r = 0; r < 4; ++r)
            if (lo16 == hi4 * 4 + r) diag += acc[r] + acc2[r];
        }
      }
    }
    if (c < 3) {   // write next chunk into the other buffer
      char* buf2 = (char*)Bs[(c + 1) & 1];
#pragma unroll
      for (int j = 0; j < 4; ++j) {
        float4 f0 = tmp[2 * j], f1 = tmp[2 * j + 1];
        uint4v pk = { pk2(f0.x, f0.y), pk2(f0.z, f0.w),
                      pk2(f1.x, f1.y), pk2(f1.z, f1.w) };
        int byte = sr * 256 + ((sq * 64 + j * 16) ^ ((sr & 7) << 4));
        *(uint4v*)(buf2 + byte) = pk;
      }
    }
    __syncthreads();
  }

  // ---- reduction: sum partial sumexp across 16-lane col groups ----
  float part = 0.f;
#pragma unroll
  for (int mt = 0; mt < 4; ++mt)
#pragma unroll
    for (int r = 0; r < 4; ++r) {
      float v1 = s1[mt][r], v2 = s2[mt][r];
#pragma unroll
      for (int m = 1; m < 16; m <<= 1) {
        v1 += __shfl_xor(v1, m, 64);
        v2 += __shfl_xor(v2, m, 64);
      }
      if (lo16 == 0)
        part += __builtin_amdgcn_logf(v1) + __builtin_amdgcn_logf(v2);
    }
  part -= diag;   // both in log2 units; scale by ln2 at the end
#pragma unroll
  for (int m = 1; m < 64; m <<= 1) part += __shfl_xor(part, m, 64);

  float* red = (float*)Bs[0];   // Bs no longer needed
  if (lane == 0) red[w] = part;
  __syncthreads();
  if (tid == 0) {
    float t = 0.f;
#pragma unroll
    for (int i = 0; i < 8; ++i) t += red[i];
    atomicAdd(out, t * (float)(0.69314718055994530942 / 131072.0));
  }
}

extern "C" void kernel_launch(void* const* d_in, const int* in_sizes, int n_in,
                              void* d_out, int out_size, void* d_ws, size_t ws_size,
                              hipStream_t stream) {
  const float* f_t      = (const float*)d_in[0];
  const float* fmap_t   = (const float*)d_in[1];
  const float* fmap_tp1 = (const float*)d_in[2];
  const float* W1       = (const float*)d_in[3];
  const float* b1       = (const float*)d_in[4];
  const float* W2       = (const float*)d_in[5];
  const float* b2       = (const float*)d_in[6];

  unsigned short* pred1 = (unsigned short*)d_ws;            // 512*128 bf16
  unsigned short* pred2 = pred1 + 512 * 128;                // 256*512*128 bf16
  float* out = (float*)d_out;

  hipMemsetAsync(out, 0, sizeof(float), stream);
  pred1_kernel<<<256, 256, 0, stream>>>(f_t, W1, b1, pred1);
  pred2_kernel<<<256, 512, 0, stream>>>(fmap_t, W2, b2, pred2);
  loss_kernel<<<256, 512, 0, stream>>>(fmap_tp1, pred1, pred2, out);
}

// Round 3
// 405.553 us; speedup vs baseline: 1.1923x; 1.1923x over previous
//
#include <hip/hip_runtime.h>
#include <hip/hip_bf16.h>

typedef __bf16 bf16x8 __attribute__((ext_vector_type(8)));
typedef float  f32x4  __attribute__((ext_vector_type(4)));
typedef unsigned int uint4v __attribute__((ext_vector_type(4)));

#define LOG2E 1.4426950408889634f

__device__ __forceinline__ unsigned int pk2(float a, float b) {
  unsigned short lo = __builtin_bit_cast(unsigned short, (__bf16)a);
  unsigned short hi = __builtin_bit_cast(unsigned short, (__bf16)b);
  return (unsigned int)lo | ((unsigned int)hi << 16);
}

// ---------------- pred1 = (f_t @ W1^T + b1) * log2e  -> bf16 [512][128] ----
__global__ __launch_bounds__(256) void pred1_kernel(
    const float* __restrict__ f_t, const float* __restrict__ W1,
    const float* __restrict__ b1, unsigned short* __restrict__ pred1) {
  int t = blockIdx.x * 256 + threadIdx.x;   // 65536 threads
  int n = t >> 7, d = t & 127;
  const float4* fr = (const float4*)(f_t + n * 256);
  const float4* wr = (const float4*)(W1 + d * 256);
  float acc = 0.f;
#pragma unroll 16
  for (int e = 0; e < 64; ++e) {
    float4 a = fr[e], b = wr[e];
    acc += a.x * b.x; acc += a.y * b.y; acc += a.z * b.z; acc += a.w * b.w;
  }
  float v = (acc + b1[d]) * LOG2E;
  pred1[t] = __builtin_bit_cast(unsigned short, (__bf16)v);
}

// ---------------- W2 fp32 -> bf16 packed [128][128] ------------------------
__global__ __launch_bounds__(256) void w2pack_kernel(
    const float* __restrict__ W2, unsigned short* __restrict__ w2p) {
  int i = blockIdx.x * 256 + threadIdx.x;   // 16384
  w2p[i] = __builtin_bit_cast(unsigned short, (__bf16)W2[i]);
}

// -------- pred2[yx] = (fmap_t[:,y,x,:] @ W2^T + b2) * log2e -> bf16 --------
// grid 1024 = (yx, quarter); 256 threads; W2 read from L1-resident packed buf
__global__ __launch_bounds__(256, 4) void pred2_kernel(
    const float* __restrict__ fmap_t, const unsigned short* __restrict__ w2p,
    const float* __restrict__ b2, unsigned short* __restrict__ pred2) {
  const int blk = blockIdx.x;
  const int yx = blk & 255, qr = blk >> 8;
  const int tid = threadIdx.x;
  const int w = tid >> 6, lane = tid & 63;
  const int lo16 = lane & 15, hi4 = lane >> 4;
  const int rowbase = qr * 128 + w * 32;

  bf16x8 a[2][4];
#pragma unroll
  for (int mt = 0; mt < 2; ++mt)
#pragma unroll
    for (int ks = 0; ks < 4; ++ks) {
      int row = rowbase + 16 * mt + lo16;
      int k = 32 * ks + 8 * hi4;
      const float* p = fmap_t + (size_t)row * 32768 + yx * 128 + k;
      float4 f0 = ((const float4*)p)[0], f1 = ((const float4*)p)[1];
      bf16x8 av;
      av[0] = (__bf16)f0.x; av[1] = (__bf16)f0.y; av[2] = (__bf16)f0.z; av[3] = (__bf16)f0.w;
      av[4] = (__bf16)f1.x; av[5] = (__bf16)f1.y; av[6] = (__bf16)f1.z; av[7] = (__bf16)f1.w;
      a[mt][ks] = av;
    }

  unsigned short* outb = pred2 + (size_t)yx * 65536;
#pragma unroll
  for (int nt = 0; nt < 8; ++nt) {
    bf16x8 bw[4];
#pragma unroll
    for (int ks = 0; ks < 4; ++ks)
      bw[ks] = *(const bf16x8*)(w2p + (nt * 16 + lo16) * 128 + 32 * ks + 8 * hi4);
    float b2v = b2[nt * 16 + lo16];
#pragma unroll
    for (int mt = 0; mt < 2; ++mt) {
      f32x4 acc = {0.f, 0.f, 0.f, 0.f};
#pragma unroll
      for (int ks = 0; ks < 4; ++ks)
        acc = __builtin_amdgcn_mfma_f32_16x16x32_bf16(a[mt][ks], bw[ks], acc, 0, 0, 0);
      int row = rowbase + 16 * mt + hi4 * 4;
      int dcol = nt * 16 + lo16;
#pragma unroll
      for (int r = 0; r < 4; ++r) {
        float v = (acc[r] + b2v) * LOG2E;
        outb[(size_t)(row + r) * 128 + dcol] = __builtin_bit_cast(unsigned short, (__bf16)v);
      }
    }
  }
}

// ------------- main: grid 512 = (yx, branch); per block: lse rows ----------
__global__ __launch_bounds__(512, 4) void loss_kernel(
    const float* __restrict__ fmap_tp1,
    const unsigned short* __restrict__ pred1,
    const unsigned short* __restrict__ pred2,
    float* __restrict__ out) {
  __shared__ unsigned short Bs[2][8192];   // 2 x 16KB swizzled bf16 chunks (64 rows)
  const int blk = blockIdx.x;
  const int yx = blk & 255;
  const unsigned short* predb =
      (blk & 256) ? (pred2 + (size_t)yx * 65536) : pred1;
  const int tid = threadIdx.x;
  const int w = tid >> 6, lane = tid & 63;
  const int lo16 = lane & 15, hi4 = lane >> 4;
  const int sr = tid >> 3, sq = tid & 7;    // staging: 64 rows x 8 thr/row

  // A fragments (one branch only -> 64 VGPRs)
  bf16x8 a[4][4];
#pragma unroll
  for (int mt = 0; mt < 4; ++mt)
#pragma unroll
    for (int ks = 0; ks < 4; ++ks) {
      int row = w * 64 + 16 * mt + lo16;
      int k = 32 * ks + 8 * hi4;
      a[mt][ks] = *(const bf16x8*)(predb + row * 128 + k);
    }

  float s[4][4];
#pragma unroll
  for (int mt = 0; mt < 4; ++mt)
#pragma unroll
    for (int r = 0; r < 4; ++r) s[mt][r] = 0.f;
  float diag = 0.f;

  const float* srcbase = fmap_tp1 + (size_t)sr * 32768 + yx * 128 + sq * 16;
  const int wbyte0 = sr * 256 + ((sq * 32) ^ ((sr & 7) << 4));
  const int wbyte1 = sr * 256 + ((sq * 32 + 16) ^ ((sr & 7) << 4));

  float4 tmp[4];
  // stage chunk 0
#pragma unroll
  for (int j = 0; j < 4; ++j) tmp[j] = ((const float4*)srcbase)[j];
  {
    char* buf = (char*)Bs[0];
    uint4v p0 = { pk2(tmp[0].x, tmp[0].y), pk2(tmp[0].z, tmp[0].w),
                  pk2(tmp[1].x, tmp[1].y), pk2(tmp[1].z, tmp[1].w) };
    uint4v p1 = { pk2(tmp[2].x, tmp[2].y), pk2(tmp[2].z, tmp[2].w),
                  pk2(tmp[3].x, tmp[3].y), pk2(tmp[3].z, tmp[3].w) };
    *(uint4v*)(buf + wbyte0) = p0;
    *(uint4v*)(buf + wbyte1) = p1;
  }
  __syncthreads();

  for (int c = 0; c < 8; ++c) {
    if (c < 7) {   // T14: issue next chunk's global loads early
      const float4* src = (const float4*)(srcbase + (size_t)(c + 1) * 64 * 32768);
#pragma unroll
      for (int j = 0; j < 4; ++j) tmp[j] = src[j];
    }
    const char* buf = (const char*)Bs[c & 1];
#pragma unroll
    for (int nt = 0; nt < 4; ++nt) {
      bf16x8 bw[4];
#pragma unroll
      for (int ks = 0; ks < 4; ++ks) {
        int m = nt * 16 + lo16;
        int kb = (32 * ks + 8 * hi4) * 2;
        bw[ks] = *(const bf16x8*)(buf + m * 256 + (kb ^ ((m & 7) << 4)));
      }
      const int coltile = c * 64 + nt * 16;
#pragma unroll
      for (int mt = 0; mt < 4; ++mt) {
        f32x4 acc = {0.f, 0.f, 0.f, 0.f};
#pragma unroll
        for (int ks = 0; ks < 4; ++ks)
          acc = __builtin_amdgcn_mfma_f32_16x16x32_bf16(a[mt][ks], bw[ks], acc, 0, 0, 0);
#pragma unroll
        for (int r = 0; r < 4; ++r) s[mt][r] += __builtin_amdgcn_exp2f(acc[r]);
        if (coltile == w * 64 + mt * 16) {   // diagonal tile (wave-uniform)
#pragma unroll
          for (int r = 0; r < 4; ++r)
            if (lo16 == hi4 * 4 + r) diag += acc[r];
        }
      }
    }
    if (c < 7) {   // write next chunk into the other buffer
      char* buf2 = (char*)Bs[(c + 1) & 1];
      uint4v p0 = { pk2(tmp[0].x, tmp[0].y), pk2(tmp[0].z, tmp[0].w),
                    pk2(tmp[1].x, tmp[1].y), pk2(tmp[1].z, tmp[1].w) };
      uint4v p1 = { pk2(tmp[2].x, tmp[2].y), pk2(tmp[2].z, tmp[2].w),
                    pk2(tmp[3].x, tmp[3].y), pk2(tmp[3].z, tmp[3].w) };
      *(uint4v*)(buf2 + wbyte0) = p0;
      *(uint4v*)(buf2 + wbyte1) = p1;
    }
    __syncthreads();
  }

  // ---- reduction: sum partial sumexp across each 16-lane col group ----
  float part = 0.f;
#pragma unroll
  for (int mt = 0; mt < 4; ++mt)
#pragma unroll
    for (int r = 0; r < 4; ++r) {
      float v = s[mt][r];
#pragma unroll
      for (int m = 1; m < 16; m <<= 1) v += __shfl_xor(v, m, 64);
      if (lo16 == 0) part += __builtin_amdgcn_logf(v);
    }
  part -= diag;   // log2 units; scale by ln2 at the end
#pragma unroll
  for (int m = 1; m < 64; m <<= 1) part += __shfl_xor(part, m, 64);

  __syncthreads();               // all waves done with Bs before reuse
  float* red = (float*)Bs;
  if (lane == 0) red[w] = part;
  __syncthreads();
  if (tid == 0) {
    float t = 0.f;
#pragma unroll
    for (int i = 0; i < 8; ++i) t += red[i];
    atomicAdd(out, t * (float)(0.69314718055994530942 / 131072.0));
  }
}

extern "C" void kernel_launch(void* const* d_in, const int* in_sizes, int n_in,
                              void* d_out, int out_size, void* d_ws, size_t ws_size,
                              hipStream_t stream) {
  const float* f_t      = (const float*)d_in[0];
  const float* fmap_t   = (const float*)d_in[1];
  const float* fmap_tp1 = (const float*)d_in[2];
  const float* W1       = (const float*)d_in[3];
  const float* b1       = (const float*)d_in[4];
  const float* W2       = (const float*)d_in[5];
  const float* b2       = (const float*)d_in[6];

  unsigned short* pred1 = (unsigned short*)d_ws;            // 512*128 bf16
  unsigned short* pred2 = pred1 + 512 * 128;                // 256*512*128 bf16
  unsigned short* w2p   = pred2 + (size_t)256 * 512 * 128;  // 128*128 bf16
  float* out = (float*)d_out;

  hipMemsetAsync(out, 0, sizeof(float), stream);
  pred1_kernel<<<256, 256, 0, stream>>>(f_t, W1, b1, pred1);
  w2pack_kernel<<<64, 256, 0, stream>>>(W2, w2p);
  pred2_kernel<<<1024, 256, 0, stream>>>(fmap_t, w2p, b2, pred2);
  loss_kernel<<<512, 512, 0, stream>>>(fmap_tp1, pred1, pred2, out);
}